// Round 4
// baseline (1736.856 us; speedup 1.0000x reference)
//
#include <hip/hip_runtime.h>
#include <hip/hip_fp16.h>

// Wavefront-pipelined 20-layer ReLU RNN for MI355X — round 4.
// vs round 3: __syncthreads (vmcnt(0) drain) removed from the step loop.
//  - ONE raw barrier per step: "s_waitcnt lgkmcnt(0); s_barrier" (LDS hazards
//    only). lH is double-buffered so the MFMA-read vs epilogue-write hazard
//    spans the single barrier.
//  - All loop vmem is inline asm (global_load_dwordx4 / store_dwordx2 with
//    sc0 sc1 = MALL-coherent). Exact vmcnt choreography: unscramble waits
//    vmcnt(4) (pf loads done, 4 ring stores left in flight). FIFO order =>
//    waiting the pf loads proves all OLDER ring stores drained, so the
//    produced-counter can be published at the next barrier with NO drain.
//  - Publish delayed one step (prod = t-1 at step t); deep polls target t+3
//    (upstream prod, tid64) and t-14 (downstream cons, tid128) — cached, so
//    they almost never issue a load. Wave 0 only publishes (fire-and-forget).
//  - Layer 0: x preloaded to LDS as fp16; zero input-half of K skipped.

#define B_    128
#define T_    784
#define H_    256
#define L_    20
#define C_    10
#define G_    8      // batch slices
#define BM_   16     // batch rows per block
#define RING_ 16     // ring slots (power of 2)
#define SW_   264    // LDS row stride in halves (256 + 8; 16B-aligned rows)
#define RQW_  1024   // u64 words per ring slot (16*256 halves)

typedef _Float16 v8h __attribute__((ext_vector_type(8)));
typedef float    v4f __attribute__((ext_vector_type(4)));
typedef unsigned long long u64;

union U4H  { uint4 u4; u64 u[2]; _Float16 h[8]; };
union U64H { u64 u; _Float16 h[4]; };

__device__ __forceinline__ uint4 ld16_coh(const void* p) {
    uint4 r;
    asm volatile("global_load_dwordx4 %0, %1, off sc0 sc1" : "=v"(r) : "v"(p));
    return r;
}
__device__ __forceinline__ void st8_coh(void* p, u64 v) {
    asm volatile("global_store_dwordx2 %0, %1, off sc0 sc1" :: "v"(p), "v"(v));
}
#define BAR_TOP() asm volatile("s_waitcnt lgkmcnt(0)\ns_barrier" ::: "memory")

__global__ __launch_bounds__(256, 1)
void rnn_wavefront(const float* __restrict__ x,
                   const float* __restrict__ W_ih0,
                   const float* __restrict__ b_ih0,
                   const float* __restrict__ W_ih,
                   const float* __restrict__ b_ih,
                   const float* __restrict__ W_hh,
                   const float* __restrict__ b_hh,
                   const float* __restrict__ W_fc,
                   const float* __restrict__ b_fc,
                   float* __restrict__ out,
                   unsigned* __restrict__ prod,    // [L_][G_] monotonic
                   unsigned* __restrict__ cons,    // [L_][G_] monotonic
                   u64* __restrict__ ring)         // [L_][G_][RING_][RQW_]
{
    const int l    = blockIdx.x >> 3;
    const int g    = blockIdx.x & 7;
    const int tid  = threadIdx.x;
    const int lane = tid & 63;
    const int wave = tid >> 6;
    const int quad = lane >> 4;
    const int s16  = lane & 15;
    const int nbase = wave * 64;   // each wave owns 64 output columns

    __shared__ __align__(16) _Float16 bufX[2][BM_][SW_]; // input-from-below, dbuf
    __shared__ __align__(16) _Float16 lH[2][BM_][SW_];   // own h, dbuf
    __shared__ _Float16 lxT[BM_][T_];                    // layer-0 x tile (fp16)

    // zero LDS h-state (h0 = 0; both parities; bufX for l==0 stays unused)
    for (int i = tid; i < 2 * BM_ * SW_; i += 256) {
        (&bufX[0][0][0])[i] = (_Float16)0.f;
        (&lH[0][0][0])[i]   = (_Float16)0.f;
    }
    if (l == 0) {   // preload x tile to LDS (removes ALL per-step vmem for l=0)
        for (int m = 0; m < BM_; ++m)
            for (int j = tid; j < T_; j += 256)
                lxT[m][j] = (_Float16)x[(size_t)(g * BM_ + m) * T_ + j];
    }

    // ---- weight B-fragments: lane holds B[k=quad*8+i][n=lane&15] ----
    v8h wf[16][4];
#pragma unroll
    for (int kt = 0; kt < 16; ++kt) {
        const int k0 = kt * 32 + quad * 8;
#pragma unroll
        for (int nt = 0; nt < 4; ++nt) {
            const int j = nbase + nt * 16 + s16;
            v8h w;
            if (kt < 8) {
                if (l == 0) {
#pragma unroll
                    for (int i = 0; i < 8; ++i) w[i] = (_Float16)0.f;
                } else {
                    const float* src = &W_ih[(((size_t)(l - 1) * H_) + j) * H_ + k0];
#pragma unroll
                    for (int i = 0; i < 8; ++i) w[i] = (_Float16)src[i];
                }
            } else {
                const float* src = &W_hh[(((size_t)l * H_) + j) * H_ + (k0 - 256)];
#pragma unroll
                for (int i = 0; i < 8; ++i) w[i] = (_Float16)src[i];
            }
            wf[kt][nt] = w;
        }
    }

    float bias[4], w0v[4];
#pragma unroll
    for (int nt = 0; nt < 4; ++nt) {
        const int j = nbase + nt * 16 + s16;
        bias[nt] = b_hh[l * H_ + j] + ((l == 0) ? b_ih0[j] : b_ih[(l - 1) * H_ + j]);
        w0v[nt]  = (l == 0) ? W_ih0[j] : 0.f;
    }

    unsigned* upprod = prod + ((l > 0 ? l - 1 : 0) * G_ + g);
    unsigned* myprod = prod + (l * G_ + g);
    unsigned* mycons = cons + (l * G_ + g);
    unsigned* dncons = cons + (((l < L_ - 1) ? l + 1 : l) * G_ + g);
    u64* myring = ring + ((size_t)(l * G_ + g) * RING_) * RQW_;
    u64* upring = ring + ((size_t)((l > 0 ? l - 1 : 0) * G_ + g) * RING_) * RQW_;

    unsigned pSeen = 0, cSeen = 0;   // live in tid64 / tid128 respectively

    // ---- prologue (l>0): blocking-acquire slot 0 into bufX[0] ----
    if (l > 0) {
        if (tid == 64) {   // pSeen owner polls; target 2 covers pf(slot1) at t=0
            while (pSeen < 2u) {
                pSeen = __hip_atomic_load(upprod, __ATOMIC_RELAXED,
                                          __HIP_MEMORY_SCOPE_AGENT);
                if (pSeen < 2u) __builtin_amdgcn_s_sleep(2);
            }
        }
        __syncthreads();   // broadcast guarantee (one-time; full sync fine)
        const u64* s0 = upring + (size_t)tid * 4;   // column n=tid, rows 0..15
        U4H a, b;
        a.u4 = ld16_coh(s0);
        b.u4 = ld16_coh(s0 + 2);
        asm volatile("s_waitcnt vmcnt(0)" ::: "memory");
#pragma unroll
        for (int r = 0; r < 8; ++r) {
            bufX[0][r][tid]     = a.h[r];
            bufX[0][8 + r][tid] = b.h[r];
        }
    }

    for (int t = 0; t < T_; ++t) {
        // ---- single barrier: LDS writes of step t-1 visible; every wave's
        // ring stores of slot t-2 proven drained (via its unscramble wait).
        BAR_TOP();

        if (tid == 0) {   // fire-and-forget publishes
            if (l < L_ - 1 && t >= 2)
                __hip_atomic_store(myprod, (unsigned)(t - 1), __ATOMIC_RELAXED,
                                   __HIP_MEMORY_SCOPE_AGENT);   // slots 0..t-2
            if (l > 0)
                __hip_atomic_store(mycons, (unsigned)(t + 1), __ATOMIC_RELAXED,
                                   __HIP_MEMORY_SCOPE_AGENT);   // slot t consumed
        }
        if (tid == 64 && l > 0 && t + 2 < T_) {        // guards pf(t+2) at top(t+1)
            const unsigned tgt = (unsigned)(t + 3);
            while (pSeen < tgt) {
                pSeen = __hip_atomic_load(upprod, __ATOMIC_RELAXED,
                                          __HIP_MEMORY_SCOPE_AGENT);
                if (pSeen < tgt) __builtin_amdgcn_s_sleep(2);
            }
        }
        if (tid == 128 && l < L_ - 1 && t >= 15) {     // guards stores(t+1)
            const unsigned tgt = (unsigned)(t - 14);
            while (cSeen < tgt) {
                cSeen = __hip_atomic_load(dncons, __ATOMIC_RELAXED,
                                          __HIP_MEMORY_SCOPE_AGENT);
                if (cSeen < tgt) __builtin_amdgcn_s_sleep(2);
            }
        }

        // ---- prefetch issue: slot t+1 -> VGPRs (guarantee from step t-1 poll,
        // broadcast by BAR_TOP) ----
        const bool doPf = (l > 0) && (t + 1 < T_);
        U4H pfa, pfb;
        if (doPf) {
            const u64* src = upring + (size_t)((t + 1) & (RING_ - 1)) * RQW_
                                    + (size_t)tid * 4;
            pfa.u4 = ld16_coh(src);
            pfb.u4 = ld16_coh(src + 2);
        }

        // ---- MFMA: acc = [X(t) | h(t-1)] x W^T ----
        v4f acc[4];
#pragma unroll
        for (int nt = 0; nt < 4; ++nt) acc[nt] = (v4f){0.f, 0.f, 0.f, 0.f};
        if (l > 0) {   // layer 0's input-half is identically zero — skip
#pragma unroll
            for (int kt = 0; kt < 8; ++kt) {
                v8h a = *(const v8h*)&bufX[t & 1][s16][kt * 32 + quad * 8];
#pragma unroll
                for (int nt = 0; nt < 4; ++nt)
                    acc[nt] = __builtin_amdgcn_mfma_f32_16x16x32_f16(a, wf[kt][nt], acc[nt], 0, 0, 0);
            }
        }
#pragma unroll
        for (int kt = 8; kt < 16; ++kt) {
            v8h a = *(const v8h*)&lH[t & 1][s16][(kt - 8) * 32 + quad * 8];
#pragma unroll
            for (int nt = 0; nt < 4; ++nt)
                acc[nt] = __builtin_amdgcn_mfma_f32_16x16x32_f16(a, wf[kt][nt], acc[nt], 0, 0, 0);
        }

        float xv[4];
        if (l == 0) {
#pragma unroll
            for (int r = 0; r < 4; ++r) xv[r] = (float)lxT[quad * 4 + r][t];
        }

        // ---- epilogue: relu(acc+bias) -> lH[(t+1)&1] + ring stores from regs ----
        u64* const slot = myring + (size_t)(t & (RING_ - 1)) * RQW_;
#pragma unroll
        for (int nt = 0; nt < 4; ++nt) {
            const int n = nbase + nt * 16 + s16;
            U64H pk;
#pragma unroll
            for (int r = 0; r < 4; ++r) {
                float v = acc[nt][r] + bias[nt];
                if (l == 0) v += xv[r] * w0v[nt];
                v = fmaxf(v, 0.f);
                const _Float16 hv = (_Float16)v;
                lH[(t + 1) & 1][quad * 4 + r][n] = hv;
                pk.h[r] = hv;
            }
            if (l < L_ - 1)
                st8_coh(&slot[(size_t)n * 4 + quad], pk.u);
        }

        // ---- unscramble pf -> bufX[(t+1)&1]. vmcnt(4): pf loads complete,
        // 4 ring stores of slot t left in flight; all older stores drained. ----
        if (doPf) {
            if (l == L_ - 1) asm volatile("s_waitcnt vmcnt(0)" ::: "memory");
            else             asm volatile("s_waitcnt vmcnt(4)" ::: "memory");
#pragma unroll
            for (int r = 0; r < 8; ++r) {
                bufX[(t + 1) & 1][r][tid]     = pfa.h[r];
                bufX[(t + 1) & 1][8 + r][tid] = pfb.h[r];
            }
        }
    }

    // ---- final: drain everything, publish prod = T (covers last 2 slots) ----
    asm volatile("s_waitcnt vmcnt(0) lgkmcnt(0)\ns_barrier" ::: "memory");
    if (tid == 0 && l < L_ - 1)
        __hip_atomic_store(myprod, (unsigned)T_, __ATOMIC_RELAXED,
                           __HIP_MEMORY_SCOPE_AGENT);

    // ---- final FC (layer 19): out = h_T @ W_fc^T + b_fc; h_T in lH[T_&1=0] ----
    if (l == L_ - 1 && tid < BM_ * C_) {
        const int bl = tid / C_;
        const int c  = tid % C_;
        float sum = b_fc[c];
        for (int k = 0; k < H_; ++k) sum += (float)lH[0][bl][k] * W_fc[c * H_ + k];
        out[(size_t)(g * BM_ + bl) * C_ + c] = sum;
    }
}

extern "C" void kernel_launch(void* const* d_in, const int* in_sizes, int n_in,
                              void* d_out, int out_size, void* d_ws, size_t ws_size,
                              hipStream_t stream) {
    const float* x     = (const float*)d_in[0];
    const float* W_ih0 = (const float*)d_in[1];
    const float* b_ih0 = (const float*)d_in[2];
    const float* W_ih  = (const float*)d_in[3];
    const float* b_ih  = (const float*)d_in[4];
    const float* W_hh  = (const float*)d_in[5];
    const float* b_hh  = (const float*)d_in[6];
    const float* W_fc  = (const float*)d_in[7];
    const float* b_fc  = (const float*)d_in[8];
    float* out = (float*)d_out;

    const size_t cntBytes = (size_t)L_ * G_ * sizeof(unsigned);   // 640 B each
    unsigned* prod = (unsigned*)d_ws;
    unsigned* cons = (unsigned*)((char*)d_ws + cntBytes);
    u64* ring      = (u64*)((char*)d_ws + 2 * cntBytes);          // 16B-aligned

    hipMemsetAsync(d_ws, 0, 2 * cntBytes, stream);

    rnn_wavefront<<<dim3(L_ * G_), dim3(256), 0, stream>>>(
        x, W_ih0, b_ih0, W_ih, b_ih, W_hh, b_hh, W_fc, b_fc,
        out, prod, cons, ring);
}